// Round 4
// baseline (570.312 us; speedup 1.0000x reference)
//
#include <hip/hip_runtime.h>
#include <cstdint>
#include <cstddef>

#define D_MODEL 1024
#define NH      16
#define HD      64
#define B_SZ    32
#define SEQ     1500
#define MROWS   (B_SZ * SEQ)   // 48000
#define KD      1024

typedef __attribute__((ext_vector_type(8))) short bf16x8;
typedef __attribute__((ext_vector_type(4))) float f32x4;
typedef unsigned short u16;

__device__ __forceinline__ u16 f2b(float f) {
  unsigned int x = __float_as_uint(f);
  x = (x + 0x7FFFu + ((x >> 16) & 1u)) >> 16;   // RNE
  return (u16)x;
}

// ---------------- fused cast f32->bf16 (blocks <3072) + q-projection rider (blocks >=3072) ----------------
#define CAST_BLOCKS 3072
#define QPROJ_BLOCKS 128   // 4 per batch, 256 outputs each

__global__ __launch_bounds__(256) void cast_all_q(const float* __restrict__ enc,
                                                  const float* __restrict__ Wk,
                                                  const float* __restrict__ Wv,
                                                  const float* __restrict__ hs,
                                                  const float* __restrict__ Wq,
                                                  const float* __restrict__ bq,
                                                  u16* __restrict__ encb,
                                                  u16* __restrict__ wkvb,
                                                  float* __restrict__ qs) {
  const int tid = threadIdx.x;
  if (blockIdx.x < CAST_BLOCKS) {
    const int NA = MROWS * KD / 8;   // 6,144,000
    const int NW = KD * KD / 8;      // 131,072
    int stride = CAST_BLOCKS * 256;
    for (int i = blockIdx.x * 256 + tid; i < NA + 2 * NW; i += stride) {
      const float* s; u16* d;
      if (i < NA)            { s = enc + (size_t)i * 8;            d = encb + (size_t)i * 8; }
      else if (i < NA + NW)  { size_t j = i - NA;      s = Wk + j * 8; d = wkvb + j * 8; }
      else                   { size_t j = i - NA - NW; s = Wv + j * 8; d = wkvb + (size_t)NW * 8 + j * 8; }
      const float4* s4 = reinterpret_cast<const float4*>(s);
      float4 a = s4[0], b = s4[1];
      u16 u[8];
      u[0]=f2b(a.x); u[1]=f2b(a.y); u[2]=f2b(a.z); u[3]=f2b(a.w);
      u[4]=f2b(b.x); u[5]=f2b(b.y); u[6]=f2b(b.z); u[7]=f2b(b.w);
      *reinterpret_cast<uint4*>(d) = *reinterpret_cast<const uint4*>(u);
    }
  } else {
    // q-proj rider: q = (hs @ Wq.T + bq) * SCALE^2, SCALE^2 = 1/8
    __shared__ float xs[D_MODEL];
    const int qb = blockIdx.x - CAST_BLOCKS;
    const int b = qb >> 2, seg = qb & 3;
    ((float4*)xs)[tid] = ((const float4*)(hs + (size_t)b * D_MODEL))[tid];
    __syncthreads();
    const int n = seg * 256 + tid;
    const float4* wp = (const float4*)(Wq + (size_t)n * D_MODEL);
    const float4* xp = (const float4*)xs;
    float a = 0.f;
    #pragma unroll 8
    for (int i = 0; i < D_MODEL / 4; ++i) {
      float4 w = wp[i], x = xp[i];
      a += w.x * x.x + w.y * x.y + w.z * x.z + w.w * x.w;
    }
    qs[(size_t)b * D_MODEL + n] = (a + bq[n]) * 0.125f;
  }
}

// ================= 128x256 bf16 MFMA GEMM, ~3 blocks/CU =================
// C[m,n] = sum_k A[m,k]*Bmat[n,k]; A [48000][1024] bf16, Bmat [2048][1024] bf16.
// nt<4 -> Kout (no bias) + fused attention scores; nt>=4 -> Vout (+bv).
#define GBM 128
#define GBN 256
#define GBK 32
#define GNT (KD / GBK)   // 32 K-tiles

__device__ __forceinline__ void stageA(const u16* __restrict__ Ag, u16* lbuf,
                                       long m0, int kt, int tid) {
  int c = tid;                        // 512 chunks of 16B (128 rows x 4)
  int r = c >> 2, cp = c & 3;
  int scp = cp ^ ((r >> 1) & 3);
  const u16* src = Ag + (m0 + r) * (long)KD + kt * GBK + scp * 8;
  __builtin_amdgcn_global_load_lds((const __attribute__((address_space(1))) void*)src,
      (__attribute__((address_space(3))) void*)(lbuf + (size_t)c * 8), 16, 0, 0);
}

__device__ __forceinline__ void stageB(const u16* __restrict__ Bg, u16* lbuf,
                                       int n0, int kt, int tid) {
  #pragma unroll
  for (int L = 0; L < 2; ++L) {
    int c = tid + L * 512;            // 1024 chunks (256 rows x 4)
    int r = c >> 2, cp = c & 3;
    int scp = cp ^ ((r >> 1) & 3);
    const u16* src = Bg + (size_t)(n0 + r) * KD + kt * GBK + scp * 8;
    __builtin_amdgcn_global_load_lds((const __attribute__((address_space(1))) void*)src,
        (__attribute__((address_space(3))) void*)(lbuf + (size_t)c * 8), 16, 0, 0);
  }
}

__device__ __forceinline__ bf16x8 ldFrag(const u16* buf, int row, int lane) {
  int r  = row + (lane & 15);
  int ch = (lane >> 4) ^ ((r >> 1) & 3);
  return *(const bf16x8*)(buf + (size_t)r * GBK + ch * 8);
}

template <bool WITH_SC>
__global__ __launch_bounds__(512, 4) void gemm_kv(const u16* __restrict__ A,
                                                  const u16* __restrict__ Bm,
                                                  const float* __restrict__ bv,
                                                  const float* __restrict__ qs,
                                                  float* __restrict__ scb,
                                                  float* __restrict__ Kout,
                                                  float* __restrict__ Vout) {
  __shared__ __align__(16) char smem[2 * (GBM + GBN) * GBK * 2];   // 48 KiB
  u16* sA0 = (u16*)smem;
  u16* sA1 = sA0 + GBM * GBK;
  u16* sB0 = sA1 + GBM * GBK;
  u16* sB1 = sB0 + GBN * GBK;

  const int tid  = threadIdx.x;
  const int lane = tid & 63;
  const int wid  = tid >> 6;
  const int wr   = wid >> 2;            // 0..1: 64-row half
  const int wc   = wid & 3;             // 0..3: 64-col quarter

  // bijective XCD swizzle (grid 3000 % 8 == 0); nt fastest within a chunk
  int bx = (blockIdx.x & 7) * (gridDim.x >> 3) + (blockIdx.x >> 3);
  const int  mt = bx >> 3;              // 0..374
  const int  nt = bx & 7;               // 0..7
  const long m0 = (long)mt * GBM;
  const int  n0 = nt * GBN;

  stageA(A, sA0, m0, 0, tid);
  stageB(Bm, sB0, n0, 0, tid);
  stageA(A, sA1, m0, 1, tid);
  stageB(Bm, sB1, n0, 1, tid);

  f32x4 acc[4][4] = {};

  for (int t = 0; t < GNT; ++t) {
    if (t == GNT - 1) { asm volatile("s_waitcnt vmcnt(0)" ::: "memory"); }
    else              { asm volatile("s_waitcnt vmcnt(3)" ::: "memory"); }
    __builtin_amdgcn_s_barrier();

    const u16* cA = (t & 1) ? sA1 : sA0;
    const u16* cB = (t & 1) ? sB1 : sB0;
    bf16x8 af[4], bfr[4];
    #pragma unroll
    for (int mf = 0; mf < 4; ++mf) af[mf]  = ldFrag(cA, wr * 64 + mf * 16, lane);
    #pragma unroll
    for (int nf = 0; nf < 4; ++nf) bfr[nf] = ldFrag(cB, wc * 64 + nf * 16, lane);
    asm volatile("s_waitcnt lgkmcnt(0)" ::: "memory");
    __builtin_amdgcn_s_barrier();

    if (t + 2 < GNT) {
      u16* pA = (t & 1) ? sA1 : sA0;
      u16* pB = (t & 1) ? sB1 : sB0;
      stageA(A, pA, m0, t + 2, tid);
      stageB(Bm, pB, n0, t + 2, tid);
    }

    #pragma unroll
    for (int mf = 0; mf < 4; ++mf)
      #pragma unroll
      for (int nf = 0; nf < 4; ++nf)
        acc[mf][nf] = __builtin_amdgcn_mfma_f32_16x16x32_bf16(af[mf], bfr[nf], acc[mf][nf], 0, 0, 0);
  }

  // ---- coalesced epilogue via LDS transpose ([32][260] f32 slabs) ----
  __syncthreads();
  float (*ep)[260] = (float(*)[260])smem;   // 33,280 B

  const bool isV = (nt >= 4);
  float* Co = isV ? Vout : Kout;
  const int ncol0 = isV ? (n0 - 1024) : n0;
  float4 bias4[4];
  #pragma unroll
  for (int k = 0; k < 4; ++k) {
    int c4 = (tid + 512 * k) & 63;
    bias4[k] = isV ? reinterpret_cast<const float4*>(bv)[(ncol0 >> 2) + c4]
                   : make_float4(0.f, 0.f, 0.f, 0.f);
  }

  #pragma unroll
  for (int p = 0; p < 4; ++p) {         // 32-row slabs
    if (wr == (p >> 1)) {
      const int mfb = (p & 1) * 2;
      #pragma unroll
      for (int mm = 0; mm < 2; ++mm)
        #pragma unroll
        for (int nf = 0; nf < 4; ++nf)
          #pragma unroll
          for (int r = 0; r < 4; ++r)
            ep[mm * 16 + (lane >> 4) * 4 + r][wc * 64 + nf * 16 + (lane & 15)] =
                acc[mfb + mm][nf][r];
    }
    __syncthreads();
    #pragma unroll
    for (int k = 0; k < 4; ++k) {
      int idx = tid + 512 * k;          // 0..2047 float4s
      int row = idx >> 6;
      int c4  = idx & 63;
      long grow = m0 + p * 32 + row;
      float4 v = *reinterpret_cast<const float4*>(&ep[row][c4 * 4]);
      v.x += bias4[k].x; v.y += bias4[k].y; v.z += bias4[k].z; v.w += bias4[k].w;
      *reinterpret_cast<float4*>(&Co[grow * D_MODEL + ncol0 + c4 * 4]) = v;
    }

    if (WITH_SC && !isV) {
      // fused attention scores: heads 4*nt..4*nt+3, rows p*32..p*32+31
      const int srow  = tid >> 4;       // 0..31
      const int shead = (tid >> 2) & 3; // 0..3
      const int sq    = tid & 3;        // k-quarter
      unsigned grow = (unsigned)(m0 + p * 32 + srow);
      unsigned b = grow / 1500u;
      unsigned s = grow - b * 1500u;
      const float* qv = qs + (size_t)b * D_MODEL + (nt * 4 + shead) * HD + sq * 16;
      const float* ev = &ep[srow][shead * 64 + sq * 16];
      float a = 0.f;
      #pragma unroll
      for (int j = 0; j < 16; j += 4) {
        float4 q4 = *(const float4*)(qv + j);
        float4 e4 = *(const float4*)(ev + j);
        a += q4.x * e4.x + q4.y * e4.y + q4.z * e4.z + q4.w * e4.w;
      }
      a += __shfl_xor(a, 1);
      a += __shfl_xor(a, 2);
      if (sq == 0)
        scb[((size_t)b * NH + nt * 4 + shead) * SEQ + s] = a;
    }
    __syncthreads();
  }
}

// ---------------- attention from precomputed scores: softmax + PV ----------------
__global__ __launch_bounds__(256) void attn_sc(const float* __restrict__ scb,
                                               const float* __restrict__ V,
                                               float* __restrict__ attnc) {
  const int bh = blockIdx.x;
  const int b = bh >> 4;
  const int h = bh & 15;
  const int tid = threadIdx.x;
  __shared__ float sc[SEQ];
  __shared__ float red[256];
  __shared__ float pv[4][HD];

  const float4* src = (const float4*)(scb + (size_t)bh * SEQ);
  float lmax = -1e30f;
  for (int i = tid; i < SEQ / 4; i += 256) {
    float4 v = src[i];
    ((float4*)sc)[i] = v;
    lmax = fmaxf(fmaxf(lmax, fmaxf(v.x, v.y)), fmaxf(v.z, v.w));
  }
  red[tid] = lmax; __syncthreads();
  for (int off = 128; off; off >>= 1) {
    if (tid < off) red[tid] = fmaxf(red[tid], red[tid + off]);
    __syncthreads();
  }
  const float mmax = red[0]; __syncthreads();

  float lsum = 0.f;
  for (int s = tid; s < SEQ; s += 256) {
    float p = __expf(sc[s] - mmax);
    sc[s] = p;
    lsum += p;
  }
  red[tid] = lsum; __syncthreads();
  for (int off = 128; off; off >>= 1) {
    if (tid < off) red[tid] += red[tid + off];
    __syncthreads();
  }
  const float inv = 1.0f / red[0];

  const int d = tid & 63;
  const int sg = tid >> 6;
  float acc = 0.f;
  for (int s = sg; s < SEQ; s += 4)
    acc += sc[s] * V[(size_t)(b * SEQ + s) * D_MODEL + h * HD + d];
  pv[sg][d] = acc;
  __syncthreads();
  if (tid < HD)
    attnc[(size_t)b * D_MODEL + h * HD + tid] =
        (pv[0][tid] + pv[1][tid] + pv[2][tid] + pv[3][tid]) * inv;
}

// ---------------- fallback attention (round-3 path, q-proj fused) ----------------
__global__ __launch_bounds__(256) void attn_kernel(const float* __restrict__ hs,
                                                   const float* __restrict__ Wq,
                                                   const float* __restrict__ bq,
                                                   const float* __restrict__ K,
                                                   const float* __restrict__ V,
                                                   float* __restrict__ attnc) {
  const int bh = blockIdx.x;
  const int b = bh >> 4;
  const int h = bh & 15;
  const int tid = threadIdx.x;
  __shared__ float xs[D_MODEL];
  __shared__ float qpart[4][HD];
  __shared__ float q_sh[HD];
  __shared__ float sc[SEQ];
  __shared__ float red[256];
  __shared__ float pv[4][HD];

  ((float4*)xs)[tid] = ((const float4*)(hs + (size_t)b * D_MODEL))[tid];
  __syncthreads();
  {
    const int d = tid & 63, p = tid >> 6;
    const float4* wq4 = (const float4*)(Wq + (size_t)(h * HD + d) * D_MODEL + p * 256);
    const float4* xs4 = (const float4*)xs + p * 64;
    float a = 0.f;
    #pragma unroll 8
    for (int i = 0; i < 64; ++i) {
      float4 w = wq4[i], x = xs4[i];
      a += w.x * x.x + w.y * x.y + w.z * x.z + w.w * x.w;
    }
    qpart[p][d] = a;
  }
  __syncthreads();
  if (tid < HD)
    q_sh[tid] = (qpart[0][tid] + qpart[1][tid] + qpart[2][tid] + qpart[3][tid]
                 + bq[h * HD + tid]) * 0.125f;
  __syncthreads();

  float lmax = -1e30f;
  for (int s = tid; s < SEQ; s += 256) {
    const float4* kp = reinterpret_cast<const float4*>(K + (size_t)(b * SEQ + s) * D_MODEL + h * HD);
    float acc = 0.f;
    #pragma unroll
    for (int i = 0; i < HD / 4; ++i) {
      float4 kv = kp[i];
      acc += kv.x * q_sh[4*i] + kv.y * q_sh[4*i+1] + kv.z * q_sh[4*i+2] + kv.w * q_sh[4*i+3];
    }
    sc[s] = acc;
    lmax = fmaxf(lmax, acc);
  }
  red[tid] = lmax; __syncthreads();
  for (int off = 128; off; off >>= 1) {
    if (tid < off) red[tid] = fmaxf(red[tid], red[tid + off]);
    __syncthreads();
  }
  const float mmax = red[0]; __syncthreads();

  float lsum = 0.f;
  for (int s = tid; s < SEQ; s += 256) {
    float p = __expf(sc[s] - mmax);
    sc[s] = p;
    lsum += p;
  }
  red[tid] = lsum; __syncthreads();
  for (int off = 128; off; off >>= 1) {
    if (tid < off) red[tid] += red[tid + off];
    __syncthreads();
  }
  const float inv = 1.0f / red[0];

  const int d = tid & 63;
  const int sg = tid >> 6;
  float acc = 0.f;
  for (int s = sg; s < SEQ; s += 4)
    acc += sc[s] * V[(size_t)(b * SEQ + s) * D_MODEL + h * HD + d];
  pv[sg][d] = acc;
  __syncthreads();
  if (tid < HD)
    attnc[(size_t)b * D_MODEL + h * HD + tid] =
        (pv[0][tid] + pv[1][tid] + pv[2][tid] + pv[3][tid]) * inv;
}

// ---------------- o-projection: 8 blocks per batch, k split 2 ----------------
__global__ __launch_bounds__(256) void oproj_kernel(const float* __restrict__ x,
                                                    const float* __restrict__ Wo,
                                                    const float* __restrict__ bo,
                                                    float* __restrict__ out) {
  const int b = blockIdx.x >> 3, ch = blockIdx.x & 7;
  const int tid = threadIdx.x;
  __shared__ float xs[D_MODEL];
  ((float4*)xs)[tid] = ((const float4*)(x + (size_t)b * D_MODEL))[tid];
  __syncthreads();
  const int n = ch * 128 + (tid >> 1);
  const int half = tid & 1;
  const float4* wp = (const float4*)(Wo + (size_t)n * D_MODEL + half * 512);
  const float4* xp = (const float4*)xs + half * 128;
  float a = 0.f;
  #pragma unroll 8
  for (int i = 0; i < 128; ++i) {
    float4 w = wp[i], xv = xp[i];
    a += w.x * xv.x + w.y * xv.y + w.z * xv.z + w.w * xv.w;
  }
  a += __shfl_xor(a, 1);
  if (!half) out[(size_t)b * D_MODEL + n] = a + bo[n];
}

// ---------------- launch ----------------
extern "C" void kernel_launch(void* const* d_in, const int* in_sizes, int n_in,
                              void* d_out, int out_size, void* d_ws, size_t ws_size,
                              hipStream_t stream) {
  const float* hs  = (const float*)d_in[0];
  const float* enc = (const float*)d_in[1];
  const float* Wq  = (const float*)d_in[2];
  const float* bq  = (const float*)d_in[3];
  const float* Wk  = (const float*)d_in[4];
  const float* Wv  = (const float*)d_in[5];
  const float* bv  = (const float*)d_in[6];
  const float* Wo  = (const float*)d_in[7];
  const float* bo  = (const float*)d_in[8];

  float* out   = (float*)d_out;
  float* attnO = out;
  float* Kout  = out + 32768;
  float* Vout  = Kout + (size_t)MROWS * D_MODEL;

  char* ws = (char*)d_ws;
  const size_t off_wkvb  = (size_t)MROWS * D_MODEL * 2;        // 98,304,000
  const size_t off_qs    = off_wkvb + 4194304;                 // +4 MB
  const size_t off_attnc = off_qs + 131072;
  const size_t off_scb   = off_attnc + 131072;
  const size_t need      = off_scb + (size_t)B_SZ * NH * SEQ * 4;  // ~105.9 MB

  u16*   encb  = (u16*)ws;
  u16*   wkvb  = (u16*)(ws + off_wkvb);
  float* qs    = (float*)(ws + off_qs);
  float* attnc = (float*)(ws + off_attnc);
  float* scb   = (float*)(ws + off_scb);

  const bool fused = (ws_size >= need);

  cast_all_q<<<CAST_BLOCKS + QPROJ_BLOCKS, 256, 0, stream>>>(enc, Wk, Wv, hs, Wq, bq,
                                                             encb, wkvb, qs);

  if (fused) {
    gemm_kv<true><<<(MROWS / GBM) * (2048 / GBN), 512, 0, stream>>>(encb, wkvb, bv, qs, scb, Kout, Vout);
    attn_sc<<<B_SZ * NH, 256, 0, stream>>>(scb, Vout, attnc);
  } else {
    gemm_kv<false><<<(MROWS / GBM) * (2048 / GBN), 512, 0, stream>>>(encb, wkvb, bv, qs, qs, Kout, Vout);
    attn_kernel<<<B_SZ * NH, 256, 0, stream>>>(hs, Wq, bq, Kout, Vout, attnc);
  }
  oproj_kernel<<<B_SZ * 8, 256, 0, stream>>>(attnc, Wo, bo, attnO);
}

// Round 5
// 463.220 us; speedup vs baseline: 1.2312x; 1.2312x over previous
//
#include <hip/hip_runtime.h>
#include <cstdint>
#include <cstddef>

#define D_MODEL 1024
#define NH      16
#define HD      64
#define B_SZ    32
#define SEQ     1500
#define MROWS   (B_SZ * SEQ)   // 48000
#define KD      1024
#define NCHUNK  4
#define CLEN    (SEQ / NCHUNK) // 375

typedef __attribute__((ext_vector_type(8))) short bf16x8;
typedef __attribute__((ext_vector_type(4))) float f32x4;
typedef unsigned short u16;

__device__ __forceinline__ u16 f2b(float f) {
  unsigned int x = __float_as_uint(f);
  x = (x + 0x7FFFu + ((x >> 16) & 1u)) >> 16;   // RNE
  return (u16)x;
}

// ---------------- fused cast f32->bf16 (blocks <3072) + q-projection rider ----------------
#define CAST_BLOCKS 3072
#define QPROJ_BLOCKS 128   // 4 per batch, 256 outputs each

__global__ __launch_bounds__(256) void cast_all_q(const float* __restrict__ enc,
                                                  const float* __restrict__ Wk,
                                                  const float* __restrict__ Wv,
                                                  const float* __restrict__ hs,
                                                  const float* __restrict__ Wq,
                                                  const float* __restrict__ bq,
                                                  u16* __restrict__ encb,
                                                  u16* __restrict__ wkvb,
                                                  float* __restrict__ qs) {
  const int tid = threadIdx.x;
  if (blockIdx.x < CAST_BLOCKS) {
    const int NA = MROWS * KD / 8;   // 6,144,000
    const int NW = KD * KD / 8;      // 131,072
    int stride = CAST_BLOCKS * 256;
    for (int i = blockIdx.x * 256 + tid; i < NA + 2 * NW; i += stride) {
      const float* s; u16* d;
      if (i < NA)            { s = enc + (size_t)i * 8;            d = encb + (size_t)i * 8; }
      else if (i < NA + NW)  { size_t j = i - NA;      s = Wk + j * 8; d = wkvb + j * 8; }
      else                   { size_t j = i - NA - NW; s = Wv + j * 8; d = wkvb + (size_t)NW * 8 + j * 8; }
      const float4* s4 = reinterpret_cast<const float4*>(s);
      float4 a = s4[0], b = s4[1];
      u16 u[8];
      u[0]=f2b(a.x); u[1]=f2b(a.y); u[2]=f2b(a.z); u[3]=f2b(a.w);
      u[4]=f2b(b.x); u[5]=f2b(b.y); u[6]=f2b(b.z); u[7]=f2b(b.w);
      *reinterpret_cast<uint4*>(d) = *reinterpret_cast<const uint4*>(u);
    }
  } else {
    // q-proj rider: q = (hs @ Wq.T + bq) * SCALE^2, SCALE^2 = 1/8
    __shared__ float xs[D_MODEL];
    const int qb = blockIdx.x - CAST_BLOCKS;
    const int b = qb >> 2, seg = qb & 3;
    ((float4*)xs)[tid] = ((const float4*)(hs + (size_t)b * D_MODEL))[tid];
    __syncthreads();
    const int n = seg * 256 + tid;
    const float4* wp = (const float4*)(Wq + (size_t)n * D_MODEL);
    const float4* xp = (const float4*)xs;
    float a = 0.f;
    #pragma unroll 8
    for (int i = 0; i < D_MODEL / 4; ++i) {
      float4 w = wp[i], x = xp[i];
      a += w.x * x.x + w.y * x.y + w.z * x.z + w.w * x.w;
    }
    qs[(size_t)b * D_MODEL + n] = (a + bq[n]) * 0.125f;
  }
}

// ================= 128x256 bf16 MFMA GEMM (round-3 proven version) =================
#define GBM 128
#define GBN 256
#define GBK 32
#define GNT (KD / GBK)   // 32 K-tiles

__device__ __forceinline__ void stageA(const u16* __restrict__ Ag, u16* lbuf,
                                       long m0, int kt, int tid) {
  int c = tid;
  int r = c >> 2, cp = c & 3;
  int scp = cp ^ ((r >> 1) & 3);
  const u16* src = Ag + (m0 + r) * (long)KD + kt * GBK + scp * 8;
  __builtin_amdgcn_global_load_lds((const __attribute__((address_space(1))) void*)src,
      (__attribute__((address_space(3))) void*)(lbuf + (size_t)c * 8), 16, 0, 0);
}

__device__ __forceinline__ void stageB(const u16* __restrict__ Bg, u16* lbuf,
                                       int n0, int kt, int tid) {
  #pragma unroll
  for (int L = 0; L < 2; ++L) {
    int c = tid + L * 512;
    int r = c >> 2, cp = c & 3;
    int scp = cp ^ ((r >> 1) & 3);
    const u16* src = Bg + (size_t)(n0 + r) * KD + kt * GBK + scp * 8;
    __builtin_amdgcn_global_load_lds((const __attribute__((address_space(1))) void*)src,
        (__attribute__((address_space(3))) void*)(lbuf + (size_t)c * 8), 16, 0, 0);
  }
}

__device__ __forceinline__ bf16x8 ldFrag(const u16* buf, int row, int lane) {
  int r  = row + (lane & 15);
  int ch = (lane >> 4) ^ ((r >> 1) & 3);
  return *(const bf16x8*)(buf + (size_t)r * GBK + ch * 8);
}

__global__ __launch_bounds__(512, 4) void gemm_kv(const u16* __restrict__ A,
                                                  const u16* __restrict__ Bm,
                                                  const float* __restrict__ bv,
                                                  float* __restrict__ Kout,
                                                  float* __restrict__ Vout) {
  __shared__ __align__(16) char smem[2 * (GBM + GBN) * GBK * 2];   // 48 KiB
  u16* sA0 = (u16*)smem;
  u16* sA1 = sA0 + GBM * GBK;
  u16* sB0 = sA1 + GBM * GBK;
  u16* sB1 = sB0 + GBN * GBK;

  const int tid  = threadIdx.x;
  const int lane = tid & 63;
  const int wid  = tid >> 6;
  const int wr   = wid >> 2;
  const int wc   = wid & 3;

  int bx = (blockIdx.x & 7) * (gridDim.x >> 3) + (blockIdx.x >> 3);
  const int  mt = bx >> 3;
  const int  nt = bx & 7;
  const long m0 = (long)mt * GBM;
  const int  n0 = nt * GBN;

  stageA(A, sA0, m0, 0, tid);
  stageB(Bm, sB0, n0, 0, tid);
  stageA(A, sA1, m0, 1, tid);
  stageB(Bm, sB1, n0, 1, tid);

  f32x4 acc[4][4] = {};

  for (int t = 0; t < GNT; ++t) {
    if (t == GNT - 1) { asm volatile("s_waitcnt vmcnt(0)" ::: "memory"); }
    else              { asm volatile("s_waitcnt vmcnt(3)" ::: "memory"); }
    __builtin_amdgcn_s_barrier();

    const u16* cA = (t & 1) ? sA1 : sA0;
    const u16* cB = (t & 1) ? sB1 : sB0;
    bf16x8 af[4], bfr[4];
    #pragma unroll
    for (int mf = 0; mf < 4; ++mf) af[mf]  = ldFrag(cA, wr * 64 + mf * 16, lane);
    #pragma unroll
    for (int nf = 0; nf < 4; ++nf) bfr[nf] = ldFrag(cB, wc * 64 + nf * 16, lane);
    asm volatile("s_waitcnt lgkmcnt(0)" ::: "memory");
    __builtin_amdgcn_s_barrier();

    if (t + 2 < GNT) {
      u16* pA = (t & 1) ? sA1 : sA0;
      u16* pB = (t & 1) ? sB1 : sB0;
      stageA(A, pA, m0, t + 2, tid);
      stageB(Bm, pB, n0, t + 2, tid);
    }

    #pragma unroll
    for (int mf = 0; mf < 4; ++mf)
      #pragma unroll
      for (int nf = 0; nf < 4; ++nf)
        acc[mf][nf] = __builtin_amdgcn_mfma_f32_16x16x32_bf16(af[mf], bfr[nf], acc[mf][nf], 0, 0, 0);
  }

  // ---- coalesced epilogue via LDS transpose ([32][260] f32 slabs) ----
  __syncthreads();
  float (*ep)[260] = (float(*)[260])smem;

  const bool isV = (nt >= 4);
  float* Co = isV ? Vout : Kout;
  const int ncol0 = isV ? (n0 - 1024) : n0;
  float4 bias4[4];
  #pragma unroll
  for (int k = 0; k < 4; ++k) {
    int c4 = (tid + 512 * k) & 63;
    bias4[k] = isV ? reinterpret_cast<const float4*>(bv)[(ncol0 >> 2) + c4]
                   : make_float4(0.f, 0.f, 0.f, 0.f);
  }

  #pragma unroll
  for (int p = 0; p < 4; ++p) {
    if (wr == (p >> 1)) {
      const int mfb = (p & 1) * 2;
      #pragma unroll
      for (int mm = 0; mm < 2; ++mm)
        #pragma unroll
        for (int nf = 0; nf < 4; ++nf)
          #pragma unroll
          for (int r = 0; r < 4; ++r)
            ep[mm * 16 + (lane >> 4) * 4 + r][wc * 64 + nf * 16 + (lane & 15)] =
                acc[mfb + mm][nf][r];
    }
    __syncthreads();
    #pragma unroll
    for (int k = 0; k < 4; ++k) {
      int idx = tid + 512 * k;
      int row = idx >> 6;
      int c4  = idx & 63;
      long grow = m0 + p * 32 + row;
      float4 v = *reinterpret_cast<const float4*>(&ep[row][c4 * 4]);
      v.x += bias4[k].x; v.y += bias4[k].y; v.z += bias4[k].z; v.w += bias4[k].w;
      *reinterpret_cast<float4*>(&Co[grow * D_MODEL + ncol0 + c4 * 4]) = v;
    }
    __syncthreads();
  }
}

// ---------------- attention pass 1: per-(b,h,chunk) partial online softmax + PV ----------------
// part[bh*4+c] = { m, l, pv[64] }  (66 floats)
__global__ __launch_bounds__(256) void attn_part(const float* __restrict__ qs,
                                                 const float* __restrict__ K,
                                                 const float* __restrict__ V,
                                                 float* __restrict__ part) {
  const int blk = blockIdx.x;          // bh*4 + c
  const int bh = blk >> 2, c = blk & 3;
  const int b = bh >> 4, h = bh & 15;
  const int tid = threadIdx.x;
  const int s0 = c * CLEN;

  __shared__ float q_sh[HD];
  __shared__ float sc[CLEN];
  __shared__ float red[256];
  __shared__ float pvs[16][HD];

  if (tid < HD) q_sh[tid] = qs[(size_t)b * D_MODEL + h * HD + tid];
  __syncthreads();

  // scores for this chunk (q already has SCALE^2 folded)
  float lmax = -1e30f;
  for (int i = tid; i < CLEN; i += 256) {
    const float4* kp = (const float4*)(K + (size_t)(b * SEQ + s0 + i) * D_MODEL + h * HD);
    float a = 0.f;
    #pragma unroll
    for (int j = 0; j < HD / 4; ++j) {
      float4 kv = kp[j];
      a += kv.x * q_sh[4*j] + kv.y * q_sh[4*j+1] + kv.z * q_sh[4*j+2] + kv.w * q_sh[4*j+3];
    }
    sc[i] = a;
    lmax = fmaxf(lmax, a);
  }
  red[tid] = lmax; __syncthreads();
  for (int off = 128; off; off >>= 1) {
    if (tid < off) red[tid] = fmaxf(red[tid], red[tid + off]);
    __syncthreads();
  }
  const float m = red[0]; __syncthreads();

  float lsum = 0.f;
  for (int i = tid; i < CLEN; i += 256) {
    float p = __expf(sc[i] - m);
    sc[i] = p;
    lsum += p;
  }
  red[tid] = lsum; __syncthreads();
  for (int off = 128; off; off >>= 1) {
    if (tid < off) red[tid] += red[tid + off];
    __syncthreads();
  }
  const float l = red[0];

  // partial PV: 16 d-quads x 16 s-groups, float4 per lane (16 B/lane)
  const int dq = tid & 15;
  const int sg = tid >> 4;
  float4 a4 = make_float4(0.f, 0.f, 0.f, 0.f);
  for (int i = sg; i < CLEN; i += 16) {
    float p = sc[i];
    float4 v4 = *(const float4*)(V + (size_t)(b * SEQ + s0 + i) * D_MODEL + h * HD + dq * 4);
    a4.x += p * v4.x; a4.y += p * v4.y; a4.z += p * v4.z; a4.w += p * v4.w;
  }
  *(float4*)&pvs[sg][dq * 4] = a4;
  __syncthreads();

  if (tid < HD) {
    float a = 0.f;
    #pragma unroll
    for (int g = 0; g < 16; ++g) a += pvs[g][tid];
    float* pp = part + (size_t)blk * 66;
    pp[2 + tid] = a;
    if (tid == 0) { pp[0] = m; pp[1] = l; }
  }
}

// ---------------- attention pass 2: combine 4 chunks per (b,h) ----------------
__global__ __launch_bounds__(64) void attn_comb(const float* __restrict__ part,
                                                float* __restrict__ attnc) {
  const int bh = blockIdx.x;
  const int b = bh >> 4, h = bh & 15;
  const int tid = threadIdx.x;
  const float* pp = part + (size_t)bh * 4 * 66;
  const float m0 = pp[0], m1 = pp[66], m2 = pp[132], m3 = pp[198];
  const float M = fmaxf(fmaxf(m0, m1), fmaxf(m2, m3));
  const float w0 = __expf(m0 - M), w1 = __expf(m1 - M),
              w2 = __expf(m2 - M), w3 = __expf(m3 - M);
  const float L = pp[1] * w0 + pp[67] * w1 + pp[133] * w2 + pp[199] * w3;
  const float o = (pp[2 + tid] * w0 + pp[68 + tid] * w1 +
                   pp[134 + tid] * w2 + pp[200 + tid] * w3) / L;
  attnc[(size_t)b * D_MODEL + h * HD + tid] = o;
}

// ---------------- o-projection: 8 blocks per batch, k split 2 ----------------
__global__ __launch_bounds__(256) void oproj_kernel(const float* __restrict__ x,
                                                    const float* __restrict__ Wo,
                                                    const float* __restrict__ bo,
                                                    float* __restrict__ out) {
  const int b = blockIdx.x >> 3, ch = blockIdx.x & 7;
  const int tid = threadIdx.x;
  __shared__ float xs[D_MODEL];
  ((float4*)xs)[tid] = ((const float4*)(x + (size_t)b * D_MODEL))[tid];
  __syncthreads();
  const int n = ch * 128 + (tid >> 1);
  const int half = tid & 1;
  const float4* wp = (const float4*)(Wo + (size_t)n * D_MODEL + half * 512);
  const float4* xp = (const float4*)xs + half * 128;
  float a = 0.f;
  #pragma unroll 8
  for (int i = 0; i < 128; ++i) {
    float4 w = wp[i], xv = xp[i];
    a += w.x * xv.x + w.y * xv.y + w.z * xv.z + w.w * xv.w;
  }
  a += __shfl_xor(a, 1);
  if (!half) out[(size_t)b * D_MODEL + n] = a + bo[n];
}

// ---------------- launch ----------------
extern "C" void kernel_launch(void* const* d_in, const int* in_sizes, int n_in,
                              void* d_out, int out_size, void* d_ws, size_t ws_size,
                              hipStream_t stream) {
  const float* hs  = (const float*)d_in[0];
  const float* enc = (const float*)d_in[1];
  const float* Wq  = (const float*)d_in[2];
  const float* bq  = (const float*)d_in[3];
  const float* Wk  = (const float*)d_in[4];
  const float* Wv  = (const float*)d_in[5];
  const float* bv  = (const float*)d_in[6];
  const float* Wo  = (const float*)d_in[7];
  const float* bo  = (const float*)d_in[8];

  float* out   = (float*)d_out;
  float* attnO = out;
  float* Kout  = out + 32768;
  float* Vout  = Kout + (size_t)MROWS * D_MODEL;

  char* ws = (char*)d_ws;
  const size_t off_wkvb  = (size_t)MROWS * D_MODEL * 2;        // 98,304,000
  const size_t off_qs    = off_wkvb + 4194304;
  const size_t off_attnc = off_qs + 131072;
  const size_t off_part  = off_attnc + 131072;                 // 2048*66*4 = 540,672 B

  u16*   encb  = (u16*)ws;
  u16*   wkvb  = (u16*)(ws + off_wkvb);
  float* qs    = (float*)(ws + off_qs);
  float* attnc = (float*)(ws + off_attnc);
  float* part  = (float*)(ws + off_part);

  cast_all_q<<<CAST_BLOCKS + QPROJ_BLOCKS, 256, 0, stream>>>(enc, Wk, Wv, hs, Wq, bq,
                                                             encb, wkvb, qs);

  gemm_kv<<<(MROWS / GBM) * (2048 / GBN), 512, 0, stream>>>(encb, wkvb, bv, Kout, Vout);

  attn_part<<<B_SZ * NH * NCHUNK, 256, 0, stream>>>(qs, Kout, Vout, part);
  attn_comb<<<B_SZ * NH, 64, 0, stream>>>(part, attnc);
  oproj_kernel<<<B_SZ * 8, 256, 0, stream>>>(attnc, Wo, bo, attnO);
}

// Round 6
// 457.139 us; speedup vs baseline: 1.2476x; 1.0133x over previous
//
#include <hip/hip_runtime.h>
#include <cstdint>
#include <cstddef>

#define D_MODEL 1024
#define NH      16
#define HD      64
#define B_SZ    32
#define SEQ     1500
#define MROWS   (B_SZ * SEQ)   // 48000
#define KD      1024
#define NCHUNK  4
#define CLEN    (SEQ / NCHUNK) // 375

typedef __attribute__((ext_vector_type(8))) short bf16x8;
typedef __attribute__((ext_vector_type(4))) float f32x4;
typedef unsigned short u16;

__device__ __forceinline__ u16 f2b(float f) {
  unsigned int x = __float_as_uint(f);
  x = (x + 0x7FFFu + ((x >> 16) & 1u)) >> 16;   // RNE
  return (u16)x;
}

// ---------------- fused cast f32->bf16 (blocks <3072) + q-projection rider ----------------
#define CAST_BLOCKS 3072
#define QPROJ_BLOCKS 64   // n-split: each block does 16 Wq rows for all 32 batches

__global__ __launch_bounds__(256) void cast_all_q(const float* __restrict__ enc,
                                                  const float* __restrict__ Wk,
                                                  const float* __restrict__ Wv,
                                                  const float* __restrict__ hs,
                                                  const float* __restrict__ Wq,
                                                  const float* __restrict__ bq,
                                                  u16* __restrict__ encb,
                                                  u16* __restrict__ wkvb,
                                                  float* __restrict__ qs) {
  const int tid = threadIdx.x;
  if (blockIdx.x < CAST_BLOCKS) {
    const int NA = MROWS * KD / 8;   // 6,144,000
    const int NW = KD * KD / 8;      // 131,072
    int stride = CAST_BLOCKS * 256;
    for (int i = blockIdx.x * 256 + tid; i < NA + 2 * NW; i += stride) {
      const float* s; u16* d;
      if (i < NA)            { s = enc + (size_t)i * 8;            d = encb + (size_t)i * 8; }
      else if (i < NA + NW)  { size_t j = i - NA;      s = Wk + j * 8; d = wkvb + j * 8; }
      else                   { size_t j = i - NA - NW; s = Wv + j * 8; d = wkvb + (size_t)NW * 8 + j * 8; }
      const float4* s4 = reinterpret_cast<const float4*>(s);
      float4 a = s4[0], b = s4[1];
      u16 u[8];
      u[0]=f2b(a.x); u[1]=f2b(a.y); u[2]=f2b(a.z); u[3]=f2b(a.w);
      u[4]=f2b(b.x); u[5]=f2b(b.y); u[6]=f2b(b.z); u[7]=f2b(b.w);
      *reinterpret_cast<uint4*>(d) = *reinterpret_cast<const uint4*>(u);
    }
  } else {
    // q-proj rider: 64 blocks, block qb covers Wq rows [qb*16, qb*16+16) for all 32 b.
    // Wq read exactly once globally; hs re-reads are L2-hot (128 KB).
    const int qb = blockIdx.x - CAST_BLOCKS;
    const int n  = qb * 16 + (tid & 15);
    const int bb = tid >> 4;                 // 0..15 -> batches bb and bb+16
    const float4* wp  = (const float4*)(Wq + (size_t)n * D_MODEL);
    const float4* x0p = (const float4*)(hs + (size_t)bb * D_MODEL);
    const float4* x1p = (const float4*)(hs + (size_t)(bb + 16) * D_MODEL);
    float a0 = 0.f, a1 = 0.f;
    #pragma unroll 8
    for (int i = 0; i < D_MODEL / 4; ++i) {
      float4 w = wp[i], x0 = x0p[i], x1 = x1p[i];
      a0 += w.x * x0.x + w.y * x0.y + w.z * x0.z + w.w * x0.w;
      a1 += w.x * x1.x + w.y * x1.y + w.z * x1.z + w.w * x1.w;
    }
    const float bqn = bq[n];
    qs[(size_t)bb * D_MODEL + n]        = (a0 + bqn) * 0.125f;   // SCALE^2 folded
    qs[(size_t)(bb + 16) * D_MODEL + n] = (a1 + bqn) * 0.125f;
  }
}

// ================= 128x256 bf16 MFMA GEMM (round-3 proven version, untouched) =================
#define GBM 128
#define GBN 256
#define GBK 32
#define GNT (KD / GBK)   // 32 K-tiles

__device__ __forceinline__ void stageA(const u16* __restrict__ Ag, u16* lbuf,
                                       long m0, int kt, int tid) {
  int c = tid;
  int r = c >> 2, cp = c & 3;
  int scp = cp ^ ((r >> 1) & 3);
  const u16* src = Ag + (m0 + r) * (long)KD + kt * GBK + scp * 8;
  __builtin_amdgcn_global_load_lds((const __attribute__((address_space(1))) void*)src,
      (__attribute__((address_space(3))) void*)(lbuf + (size_t)c * 8), 16, 0, 0);
}

__device__ __forceinline__ void stageB(const u16* __restrict__ Bg, u16* lbuf,
                                       int n0, int kt, int tid) {
  #pragma unroll
  for (int L = 0; L < 2; ++L) {
    int c = tid + L * 512;
    int r = c >> 2, cp = c & 3;
    int scp = cp ^ ((r >> 1) & 3);
    const u16* src = Bg + (size_t)(n0 + r) * KD + kt * GBK + scp * 8;
    __builtin_amdgcn_global_load_lds((const __attribute__((address_space(1))) void*)src,
        (__attribute__((address_space(3))) void*)(lbuf + (size_t)c * 8), 16, 0, 0);
  }
}

__device__ __forceinline__ bf16x8 ldFrag(const u16* buf, int row, int lane) {
  int r  = row + (lane & 15);
  int ch = (lane >> 4) ^ ((r >> 1) & 3);
  return *(const bf16x8*)(buf + (size_t)r * GBK + ch * 8);
}

__global__ __launch_bounds__(512, 4) void gemm_kv(const u16* __restrict__ A,
                                                  const u16* __restrict__ Bm,
                                                  const float* __restrict__ bv,
                                                  float* __restrict__ Kout,
                                                  float* __restrict__ Vout) {
  __shared__ __align__(16) char smem[2 * (GBM + GBN) * GBK * 2];   // 48 KiB
  u16* sA0 = (u16*)smem;
  u16* sA1 = sA0 + GBM * GBK;
  u16* sB0 = sA1 + GBM * GBK;
  u16* sB1 = sB0 + GBN * GBK;

  const int tid  = threadIdx.x;
  const int lane = tid & 63;
  const int wid  = tid >> 6;
  const int wr   = wid >> 2;
  const int wc   = wid & 3;

  int bx = (blockIdx.x & 7) * (gridDim.x >> 3) + (blockIdx.x >> 3);
  const int  mt = bx >> 3;
  const int  nt = bx & 7;
  const long m0 = (long)mt * GBM;
  const int  n0 = nt * GBN;

  stageA(A, sA0, m0, 0, tid);
  stageB(Bm, sB0, n0, 0, tid);
  stageA(A, sA1, m0, 1, tid);
  stageB(Bm, sB1, n0, 1, tid);

  f32x4 acc[4][4] = {};

  for (int t = 0; t < GNT; ++t) {
    if (t == GNT - 1) { asm volatile("s_waitcnt vmcnt(0)" ::: "memory"); }
    else              { asm volatile("s_waitcnt vmcnt(3)" ::: "memory"); }
    __builtin_amdgcn_s_barrier();

    const u16* cA = (t & 1) ? sA1 : sA0;
    const u16* cB = (t & 1) ? sB1 : sB0;
    bf16x8 af[4], bfr[4];
    #pragma unroll
    for (int mf = 0; mf < 4; ++mf) af[mf]  = ldFrag(cA, wr * 64 + mf * 16, lane);
    #pragma unroll
    for (int nf = 0; nf < 4; ++nf) bfr[nf] = ldFrag(cB, wc * 64 + nf * 16, lane);
    asm volatile("s_waitcnt lgkmcnt(0)" ::: "memory");
    __builtin_amdgcn_s_barrier();

    if (t + 2 < GNT) {
      u16* pA = (t & 1) ? sA1 : sA0;
      u16* pB = (t & 1) ? sB1 : sB0;
      stageA(A, pA, m0, t + 2, tid);
      stageB(Bm, pB, n0, t + 2, tid);
    }

    #pragma unroll
    for (int mf = 0; mf < 4; ++mf)
      #pragma unroll
      for (int nf = 0; nf < 4; ++nf)
        acc[mf][nf] = __builtin_amdgcn_mfma_f32_16x16x32_bf16(af[mf], bfr[nf], acc[mf][nf], 0, 0, 0);
  }

  // ---- coalesced epilogue via LDS transpose ([32][260] f32 slabs) ----
  __syncthreads();
  float (*ep)[260] = (float(*)[260])smem;

  const bool isV = (nt >= 4);
  float* Co = isV ? Vout : Kout;
  const int ncol0 = isV ? (n0 - 1024) : n0;
  float4 bias4[4];
  #pragma unroll
  for (int k = 0; k < 4; ++k) {
    int c4 = (tid + 512 * k) & 63;
    bias4[k] = isV ? reinterpret_cast<const float4*>(bv)[(ncol0 >> 2) + c4]
                   : make_float4(0.f, 0.f, 0.f, 0.f);
  }

  #pragma unroll
  for (int p = 0; p < 4; ++p) {
    if (wr == (p >> 1)) {
      const int mfb = (p & 1) * 2;
      #pragma unroll
      for (int mm = 0; mm < 2; ++mm)
        #pragma unroll
        for (int nf = 0; nf < 4; ++nf)
          #pragma unroll
          for (int r = 0; r < 4; ++r)
            ep[mm * 16 + (lane >> 4) * 4 + r][wc * 64 + nf * 16 + (lane & 15)] =
                acc[mfb + mm][nf][r];
    }
    __syncthreads();
    #pragma unroll
    for (int k = 0; k < 4; ++k) {
      int idx = tid + 512 * k;
      int row = idx >> 6;
      int c4  = idx & 63;
      long grow = m0 + p * 32 + row;
      float4 v = *reinterpret_cast<const float4*>(&ep[row][c4 * 4]);
      v.x += bias4[k].x; v.y += bias4[k].y; v.z += bias4[k].z; v.w += bias4[k].w;
      *reinterpret_cast<float4*>(&Co[grow * D_MODEL + ncol0 + c4 * 4]) = v;
    }
    __syncthreads();
  }
}

// ---------------- attention pass 1: per-(b,h,chunk) partial online softmax + PV ----------------
// Score phase: 16 lanes per row (lane j covers d = j*4..j*4+4), shfl_xor dot-reduce.
// part[bh*4+c] = { m, l, pv[64] }  (66 floats)
__global__ __launch_bounds__(256) void attn_part(const float* __restrict__ qs,
                                                 const float* __restrict__ K,
                                                 const float* __restrict__ V,
                                                 float* __restrict__ part) {
  const int blk = blockIdx.x;          // bh*4 + c
  const int bh = blk >> 2, c = blk & 3;
  const int b = bh >> 4, h = bh & 15;
  const int tid = threadIdx.x;
  const int s0 = c * CLEN;

  __shared__ float sc[CLEN];
  __shared__ float red[256];
  __shared__ float pvs[16][HD];

  // ---- scores: 16 rows in flight, 16 lanes/row, coalesced 4x256B segments/instr
  const int j  = tid & 15;             // d-quad
  const int rg = tid >> 4;             // row group 0..15
  const float4 q4 = *(const float4*)(qs + (size_t)b * D_MODEL + h * HD + j * 4);
  float lmax = -1e30f;
  for (int i = rg; i < CLEN; i += 16) {
    const float4 k4 = *(const float4*)(K + (size_t)(b * SEQ + s0 + i) * D_MODEL + h * HD + j * 4);
    float p = q4.x * k4.x + q4.y * k4.y + q4.z * k4.z + q4.w * k4.w;
    p += __shfl_xor(p, 1);
    p += __shfl_xor(p, 2);
    p += __shfl_xor(p, 4);
    p += __shfl_xor(p, 8);
    if (j == 0) sc[i] = p;
    lmax = fmaxf(lmax, p);
  }
  red[tid] = lmax; __syncthreads();
  for (int off = 128; off; off >>= 1) {
    if (tid < off) red[tid] = fmaxf(red[tid], red[tid + off]);
    __syncthreads();
  }
  const float m = red[0]; __syncthreads();

  float lsum = 0.f;
  for (int i = tid; i < CLEN; i += 256) {
    float p = __expf(sc[i] - m);
    sc[i] = p;
    lsum += p;
  }
  red[tid] = lsum; __syncthreads();
  for (int off = 128; off; off >>= 1) {
    if (tid < off) red[tid] += red[tid + off];
    __syncthreads();
  }
  const float l = red[0];

  // ---- partial PV: 16 d-quads x 16 s-groups, float4 per lane
  const int dq = tid & 15;
  const int sg = tid >> 4;
  float4 a4 = make_float4(0.f, 0.f, 0.f, 0.f);
  for (int i = sg; i < CLEN; i += 16) {
    float p = sc[i];
    float4 v4 = *(const float4*)(V + (size_t)(b * SEQ + s0 + i) * D_MODEL + h * HD + dq * 4);
    a4.x += p * v4.x; a4.y += p * v4.y; a4.z += p * v4.z; a4.w += p * v4.w;
  }
  *(float4*)&pvs[sg][dq * 4] = a4;
  __syncthreads();

  if (tid < HD) {
    float a = 0.f;
    #pragma unroll
    for (int g = 0; g < 16; ++g) a += pvs[g][tid];
    float* pp = part + (size_t)blk * 66;
    pp[2 + tid] = a;
    if (tid == 0) { pp[0] = m; pp[1] = l; }
  }
}

// ---------------- attention pass 2: combine 4 chunks per (b,h) ----------------
__global__ __launch_bounds__(64) void attn_comb(const float* __restrict__ part,
                                                float* __restrict__ attnc) {
  const int bh = blockIdx.x;
  const int b = bh >> 4, h = bh & 15;
  const int tid = threadIdx.x;
  const float* pp = part + (size_t)bh * 4 * 66;
  const float m0 = pp[0], m1 = pp[66], m2 = pp[132], m3 = pp[198];
  const float M = fmaxf(fmaxf(m0, m1), fmaxf(m2, m3));
  const float w0 = __expf(m0 - M), w1 = __expf(m1 - M),
              w2 = __expf(m2 - M), w3 = __expf(m3 - M);
  const float L = pp[1] * w0 + pp[67] * w1 + pp[133] * w2 + pp[199] * w3;
  const float o = (pp[2 + tid] * w0 + pp[68 + tid] * w1 +
                   pp[134 + tid] * w2 + pp[200 + tid] * w3) / L;
  attnc[(size_t)b * D_MODEL + h * HD + tid] = o;
}

// ---------------- o-projection: 8 blocks per batch, k split 2 ----------------
__global__ __launch_bounds__(256) void oproj_kernel(const float* __restrict__ x,
                                                    const float* __restrict__ Wo,
                                                    const float* __restrict__ bo,
                                                    float* __restrict__ out) {
  const int b = blockIdx.x >> 3, ch = blockIdx.x & 7;
  const int tid = threadIdx.x;
  __shared__ float xs[D_MODEL];
  ((float4*)xs)[tid] = ((const float4*)(x + (size_t)b * D_MODEL))[tid];
  __syncthreads();
  const int n = ch * 128 + (tid >> 1);
  const int half = tid & 1;
  const float4* wp = (const float4*)(Wo + (size_t)n * D_MODEL + half * 512);
  const float4* xp = (const float4*)xs + half * 128;
  float a = 0.f;
  #pragma unroll 8
  for (int i = 0; i < 128; ++i) {
    float4 w = wp[i], xv = xp[i];
    a += w.x * xv.x + w.y * xv.y + w.z * xv.z + w.w * xv.w;
  }
  a += __shfl_xor(a, 1);
  if (!half) out[(size_t)b * D_MODEL + n] = a + bo[n];
}

// ---------------- launch ----------------
extern "C" void kernel_launch(void* const* d_in, const int* in_sizes, int n_in,
                              void* d_out, int out_size, void* d_ws, size_t ws_size,
                              hipStream_t stream) {
  const float* hs  = (const float*)d_in[0];
  const float* enc = (const float*)d_in[1];
  const float* Wq  = (const float*)d_in[2];
  const float* bq  = (const float*)d_in[3];
  const float* Wk  = (const float*)d_in[4];
  const float* Wv  = (const float*)d_in[5];
  const float* bv  = (const float*)d_in[6];
  const float* Wo  = (const float*)d_in[7];
  const float* bo  = (const float*)d_in[8];

  float* out   = (float*)d_out;
  float* attnO = out;
  float* Kout  = out + 32768;
  float* Vout  = Kout + (size_t)MROWS * D_MODEL;

  char* ws = (char*)d_ws;
  const size_t off_wkvb  = (size_t)MROWS * D_MODEL * 2;        // 98,304,000
  const size_t off_qs    = off_wkvb + 4194304;
  const size_t off_attnc = off_qs + 131072;
  const size_t off_part  = off_attnc + 131072;                 // 2048*66*4 = 540,672 B

  u16*   encb  = (u16*)ws;
  u16*   wkvb  = (u16*)(ws + off_wkvb);
  float* qs    = (float*)(ws + off_qs);
  float* attnc = (float*)(ws + off_attnc);
  float* part  = (float*)(ws + off_part);

  cast_all_q<<<CAST_BLOCKS + QPROJ_BLOCKS, 256, 0, stream>>>(enc, Wk, Wv, hs, Wq, bq,
                                                             encb, wkvb, qs);

  gemm_kv<<<(MROWS / GBM) * (2048 / GBN), 512, 0, stream>>>(encb, wkvb, bv, Kout, Vout);

  attn_part<<<B_SZ * NH * NCHUNK, 256, 0, stream>>>(qs, Kout, Vout, part);
  attn_comb<<<B_SZ * NH, 64, 0, stream>>>(part, attnc);
  oproj_kernel<<<B_SZ * 8, 256, 0, stream>>>(attnc, Wo, bo, attnO);
}